// Round 9
// baseline (5081.736 us; speedup 1.0000x reference)
//
#include <hip/hip_runtime.h>
#include <cstddef>

typedef unsigned short u16;
typedef unsigned int u32;

#define N 384
#define NELEM (N*N)        // 147456
#define NCH 128
#define NMAT 256
#define EPS 1e-5f

// Muon quintic coefficients
#define QA 3.4445f
#define QB (-4.7750f)
#define QC 2.0315f

typedef __attribute__((ext_vector_type(8))) short bf16x8;   // 8 bf16 = 4 VGPRs
typedef __attribute__((ext_vector_type(4))) float f32x4;

__device__ __forceinline__ float bf2f(u16 h){ union{u32 u; float f;} v; v.u=((u32)h)<<16; return v.f; }
__device__ __forceinline__ u16 f2bf(float x){
  union{float f;u32 u;} v; v.f=x;
  u32 r=(v.u + 0x7FFFu + ((v.u>>16)&1u))>>16;   // RNE
  return (u16)r;
}

__device__ __forceinline__ float wave_sum(float v){
#pragma unroll
  for(int o=32;o>0;o>>=1) v += __shfl_down(v,o,64);
  return v;
}

__device__ __forceinline__ const float* mat_src(const float* ir, const float* vi, int m){
  return (m < NCH) ? (ir + (size_t)m*NELEM) : (vi + (size_t)(m-NCH)*NELEM);
}

__global__ void k_zero(float* __restrict__ x, int n){
  int i = blockIdx.x*256 + threadIdx.x;
  if(i < n) x[i] = 0.f;
}

// partial Frobenius^2 of (M+eps): grid (CH, 16), atomicAdd into f[mloc]
__global__ __launch_bounds__(256)
void k_frob_part(const float* __restrict__ ir, const float* __restrict__ vi,
                 float* __restrict__ f, int m0){
  int mloc = blockIdx.x;
  const float4* s4 = (const float4*)mat_src(ir, vi, m0+mloc) + blockIdx.y*(NELEM/4/16);
  float s = 0.f;
  for(int i=threadIdx.x; i<NELEM/4/16; i+=256){
    float4 v = s4[i];
    float a=v.x+EPS, b=v.y+EPS, c=v.z+EPS, d=v.w+EPS;
    s += a*a + b*b + c*c + d*d;
  }
  __shared__ float sm[4];
  int lane=threadIdx.x&63, w=threadIdx.x>>6;
  s = wave_sum(s);
  if(lane==0) sm[w]=s;
  __syncthreads();
  if(threadIdx.x==0) atomicAdd(&f[mloc], sm[0]+sm[1]+sm[2]+sm[3]);
}

// Fused: X = bf16((M+eps)*rsqrt(f)), Y = X^T.  grid (6,6,CH).
__global__ __launch_bounds__(256)
void k_init_t(const float* __restrict__ ir, const float* __restrict__ vi,
              const float* __restrict__ f, u16* __restrict__ Xg,
              u16* __restrict__ Yg, int m0){
  __shared__ u16 t[64][68];
  int mloc = blockIdx.z;
  const float* M = mat_src(ir, vi, m0+mloc);
  float inv = rsqrtf(f[mloc]);
  size_t mat = (size_t)mloc*NELEM;
  u16* X = Xg + mat; u16* Y = Yg + mat;
  int bx = blockIdx.x*64, by = blockIdx.y*64;
  int c = (threadIdx.x&15)*4, r0 = threadIdx.x>>4;
#pragma unroll
  for(int s=0;s<4;s++){
    int r = r0 + s*16;
    float4 v = *(const float4*)&M[(size_t)(by+r)*N + bx + c];
    u16 h0=f2bf((v.x+EPS)*inv), h1=f2bf((v.y+EPS)*inv);
    u16 h2=f2bf((v.z+EPS)*inv), h3=f2bf((v.w+EPS)*inv);
    ushort4 o; o.x=h0; o.y=h1; o.z=h2; o.w=h3;
    *(ushort4*)&X[(size_t)(by+r)*N + bx + c] = o;
    t[r][c]=h0; t[r][c+1]=h1; t[r][c+2]=h2; t[r][c+3]=h3;
  }
  __syncthreads();
#pragma unroll
  for(int s=0;s<4;s++){
    int r = r0 + s*16;
    ushort4 v;
    v.x=t[c+0][r]; v.y=t[c+1][r]; v.z=t[c+2][r]; v.w=t[c+3][r];
    *(ushort4*)&Y[(size_t)(bx+r)*N + by + c] = v;
  }
}

// NT GEMM, 192x192 TILES: C = alpha*(P*Q^T) + beta*D, optional transposed
// store to Tg. sym=1: 3 upper-tri tiles (00,01,11), mirror 01 into Tg.
// Full: 4 tiles. 1D grid (T*CH blocks), XCD-pinned.
//
// WHY 192: six K-loop structures (r1..r8) all hit the same per-dispatch
// time, and doubling staged bytes (r8) made it worse -> the gemm phase is
// bound by L2/L3 operand-fetch BW (~11-13 B/cy/CU). 192^2 tiles cut staged
// bytes/FLOP by 33% vs 128^2 (sym: 576KB/matrix vs 864KB; full: 1.15MB vs
// 1.73MB). K-loop skeleton = r6 proven: coop staging, 2-phase dbuf, ONE
// __syncthreads per step, glds->LDS linear dest with source-column XOR
// swizzle, inverse XOR on fragment reads.
// DIAG DEDUP (coop-safe: A slab holds ALL 192 tile rows): skip B staging,
// B-frags read the A slab.
// 4 waves; wave w: rows wm=(w&1)*96, cols wn=(w>>1)*96; acc 6x6 f32x4.
// Epilogue mirror: 192^2 tile > LDS, so 2-pass chunked (96 rows/pass,
// stride-104 padding: 16B-aligned b128 reads, ~2-way banks). C-stores and
// D-reads happen once (in the owning wave's pass).
// Trace mode (p_part!=nullptr): no C store; reduce alpha*PQ^T+beta*D
// against (M+eps).
__global__ __launch_bounds__(256)
void k_gemm(const u16* __restrict__ Pg, const u16* __restrict__ Qg,
            u16* __restrict__ Cg, u16* __restrict__ Tg,
            const u16* __restrict__ Dg, float alpha, float beta, int sym,
            const float* __restrict__ trir, const float* __restrict__ trvi,
            float* __restrict__ p_part, int m0g){
  // 48 KB: buf d at d*12288 {A: +0 (6144 u16 = 192x32), B: +6144}
  // epilogue overlay: u16 chunk[192][104] (transposed, padded) = 39936 B
  __shared__ __align__(16) u16 lds[24576];
  int tid = threadIdx.x, lane = tid&63, w = tid>>6;

  int T = sym ? 3 : 4;
  int CH = gridDim.x / T;
  int m, t;
  if((CH & 7) == 0){
    int xcd = blockIdx.x & 7;
    int b2  = blockIdx.x >> 3;
    t = b2 % T;
    m = xcd + 8*(b2 / T);
  } else {
    m = blockIdx.x / T;
    t = blockIdx.x - m*T;
  }
  int i0, j0;
  if(sym){
    const int it[3]={0,0,1};
    const int jt[3]={0,1,1};
    i0=it[t]; j0=jt[t];
  } else {
    i0 = t>>1; j0 = t&1;
  }
  bool diag = sym && (i0==j0);
  size_t mat = (size_t)m*NELEM;
  const u16* P = Pg + mat + (size_t)(i0*192)*N;
  const u16* Q = Qg + mat + (size_t)(j0*192)*N;

  // coop staging: 12 groups of 16 rows per operand; wave w stages groups
  // 3w..3w+2. source column swizzled: chunk q0 ^ ((srow>>1)&3).
  int srow = lane>>2;                       // 0..15
  int q0   = lane&3;
  int scol = (q0 ^ ((srow>>1)&3)) * 8;      // u16 offset in 32-wide k slice
  const u16* gA[3]; const u16* gB[3]; int lo[3];
#pragma unroll
  for(int s=0;s<3;s++){
    gA[s] = P + (size_t)((w*3+s)*16 + srow)*N + scol;
    gB[s] = Q + (size_t)((w*3+s)*16 + srow)*N + scol;
    lo[s] = (w*3+s)*512 + lane*8;
  }

  f32x4 acc[6][6];
#pragma unroll
  for(int r=0;r<6;r++)
#pragma unroll
    for(int c=0;c<6;c++) acc[r][c] = (f32x4)0.f;

  int wm = (w&1)*96, wn = (w>>1)*96;
  int quad = lane>>4, ln = lane&15;
  int swz = (quad ^ ((ln>>1)&3)) * 8;       // inverse swizzle for frag reads
  int ga = 6*(w&1), gb = 6*(w>>1);          // frag group bases

#define GLD(gp, loff) \
  __builtin_amdgcn_global_load_lds((const __attribute__((address_space(1))) void*)(gp), \
                                   (__attribute__((address_space(3))) void*)&lds[loff], 16, 0, 0)

  // prologue: stage k=0 into buf0
#pragma unroll
  for(int s=0;s<3;s++) GLD(gA[s], lo[s]);
  if(!diag){
#pragma unroll
    for(int s=0;s<3;s++) GLD(gB[s], 6144+lo[s]);
  }
  __syncthreads();                          // vmcnt(0) drain + barrier

  int cur = 0;
  for(int k0=0;k0<N;k0+=32){
    if(k0+32 < N){                          // prefetch next K-slice
      int nb = (cur^1)*12288;
#pragma unroll
      for(int s=0;s<3;s++) GLD(gA[s]+k0+32, nb+lo[s]);
      if(!diag){
#pragma unroll
        for(int s=0;s<3;s++) GLD(gB[s]+k0+32, nb+6144+lo[s]);
      }
    }
    int cb = cur*12288;
    int bb = diag ? cb : cb + 6144;         // diag: B-frags read the A slab
    bf16x8 af[6];
#pragma unroll
    for(int r=0;r<6;r++) af[r] = *(const bf16x8*)&lds[cb + (ga+r)*512 + ln*32 + swz];
#pragma unroll
    for(int c=0;c<6;c++){
      bf16x8 bv = *(const bf16x8*)&lds[bb + (gb+c)*512 + ln*32 + swz];
#pragma unroll
      for(int r=0;r<6;r++)
        acc[r][c] = __builtin_amdgcn_mfma_f32_16x16x32_bf16(af[r], bv, acc[r][c], 0, 0, 0);
    }
    __syncthreads();                        // prefetch landed + reads done
    cur ^= 1;
  }
#undef GLD

  // epilogue (LDS free after final in-loop barrier)
  u16* C = Cg + mat;
  const u16* D = Dg ? Dg + mat : nullptr;
  bool do_t = (Tg != nullptr) && !diag;
  bool do_tr = (p_part != nullptr);
  int rowb = i0*192 + wm, colb = j0*192 + wn;

  if(do_tr){
    const float* Mf = mat_src(trir, trvi, m0g + m);
    float ts = 0.f;
#pragma unroll
    for(int r=0;r<6;r++){
#pragma unroll
      for(int c=0;c<6;c++){
        int row0 = rowb + r*16 + quad*4;
        int col  = colb + c*16 + ln;
        float v0 = alpha*acc[r][c].x;
        float v1 = alpha*acc[r][c].y;
        float v2 = alpha*acc[r][c].z;
        float v3 = alpha*acc[r][c].w;
        if(D){
          v0 += beta*bf2f(D[(size_t)(row0+0)*N + col]);
          v1 += beta*bf2f(D[(size_t)(row0+1)*N + col]);
          v2 += beta*bf2f(D[(size_t)(row0+2)*N + col]);
          v3 += beta*bf2f(D[(size_t)(row0+3)*N + col]);
        }
        ts += v0*(Mf[(size_t)(row0+0)*N + col]+EPS)
            + v1*(Mf[(size_t)(row0+1)*N + col]+EPS)
            + v2*(Mf[(size_t)(row0+2)*N + col]+EPS)
            + v3*(Mf[(size_t)(row0+3)*N + col]+EPS);
      }
    }
    ts = wave_sum(ts);
    float* smf = (float*)lds;
    if(lane==0) smf[w] = ts;
    __syncthreads();
    if(tid==0) atomicAdd(&p_part[m0g + m], smf[0]+smf[1]+smf[2]+smf[3]);
  } else if(!do_t){
    // C store only (sym diag tiles)
#pragma unroll
    for(int r=0;r<6;r++){
#pragma unroll
      for(int c=0;c<6;c++){
        int row0 = rowb + r*16 + quad*4;
        int col  = colb + c*16 + ln;
        float v0 = alpha*acc[r][c].x;
        float v1 = alpha*acc[r][c].y;
        float v2 = alpha*acc[r][c].z;
        float v3 = alpha*acc[r][c].w;
        if(D){
          v0 += beta*bf2f(D[(size_t)(row0+0)*N + col]);
          v1 += beta*bf2f(D[(size_t)(row0+1)*N + col]);
          v2 += beta*bf2f(D[(size_t)(row0+2)*N + col]);
          v3 += beta*bf2f(D[(size_t)(row0+3)*N + col]);
        }
        C[(size_t)(row0+0)*N + col] = f2bf(v0);
        C[(size_t)(row0+1)*N + col] = f2bf(v1);
        C[(size_t)(row0+2)*N + col] = f2bf(v2);
        C[(size_t)(row0+3)*N + col] = f2bf(v3);
      }
    }
  } else {
    // C store + transposed mirror, chunked in 2 passes of 96 rows.
    // Pass p: waves with (w&1)==p compute+store their frags and stage the
    // transposed chunk [192 cols][96 rows] (stride 104), then all threads
    // stream the chunk out coalesced.
    u16* Tm = Tg + mat;
    int rbase = i0*192, cbase = j0*192;
    for(int p=0;p<2;p++){
      __syncthreads();                       // LDS free / prev chunk stored
      if((w&1)==p){
#pragma unroll
        for(int r=0;r<6;r++){
#pragma unroll
          for(int c=0;c<6;c++){
            int row0 = rowb + r*16 + quad*4;
            int col  = colb + c*16 + ln;
            float v0 = alpha*acc[r][c].x;
            float v1 = alpha*acc[r][c].y;
            float v2 = alpha*acc[r][c].z;
            float v3 = alpha*acc[r][c].w;
            if(D){
              v0 += beta*bf2f(D[(size_t)(row0+0)*N + col]);
              v1 += beta*bf2f(D[(size_t)(row0+1)*N + col]);
              v2 += beta*bf2f(D[(size_t)(row0+2)*N + col]);
              v3 += beta*bf2f(D[(size_t)(row0+3)*N + col]);
            }
            u16 h0=f2bf(v0), h1=f2bf(v1), h2=f2bf(v2), h3=f2bf(v3);
            C[(size_t)(row0+0)*N + col] = h0;
            C[(size_t)(row0+1)*N + col] = h1;
            C[(size_t)(row0+2)*N + col] = h2;
            C[(size_t)(row0+3)*N + col] = h3;
            int lcol = wn + c*16 + ln;       // 0..191
            int lrow = r*16 + quad*4;        // 0..95 (wm==p*96)
            ushort4 pk; pk.x=h0; pk.y=h1; pk.z=h2; pk.w=h3;
            *(ushort4*)&lds[lcol*104 + lrow] = pk;
          }
        }
      }
      __syncthreads();
      // stream chunk p: 192 cols x 96 rows = 2304 bf16x8 / 256 threads
#pragma unroll
      for(int it9=0; it9<9; ++it9){
        int idx  = it9*256 + tid;            // 0..2303
        int lcol = idx/12;                   // 0..191
        int ch   = idx - lcol*12;            // 0..11
        bf16x8 v = *(const bf16x8*)&lds[lcol*104 + ch*8];
        *(bf16x8*)&Tm[(size_t)(cbase+lcol)*N + rbase + p*96 + ch*8] = v;
      }
    }
  }
}

// combine with inline weights: w1=p[c]/(p[c]+p[c+128]+EPS)
__global__ __launch_bounds__(256)
void k_combine_w(const float* __restrict__ ir, const float* __restrict__ vi,
                 const float* __restrict__ p, float* __restrict__ out){
  int i = blockIdx.x*256 + threadIdx.x;
  int c = i / (NELEM/4);
  float pa = p[c], pb = p[c+NCH];
  float den = pa + pb + EPS;
  float x1 = pa/den, x2 = pb/den;
  float4 a = ((const float4*)ir)[i];
  float4 b = ((const float4*)vi)[i];
  float4 o;
  o.x = x1*a.x + x2*b.x; o.y = x1*a.y + x2*b.y;
  o.z = x1*a.z + x2*b.z; o.w = x1*a.w + x2*b.w;
  ((float4*)out)[i] = o;
}

extern "C" void kernel_launch(void* const* d_in, const int* in_sizes, int n_in,
                              void* d_out, int out_size, void* d_ws, size_t ws_size,
                              hipStream_t stream){
  const float* ir = (const float*)d_in[0];
  const float* vi = (const float*)d_in[1];
  float* out = (float*)d_out;

  // 4 bf16 ping-pong buffers of CH matrices + small fp32 tail.
  // CH<=128: live set 148 MB stays L3-resident.
  int CH = NMAT;
  while(CH > 1 && (size_t)4*CH*NELEM*2 + 4096 > ws_size) CH >>= 1;
  if(CH > 128) CH = 128;

  u16* b[4];
  for(int i=0;i<4;i++) b[i] = (u16*)d_ws + (size_t)i*CH*NELEM;
  float* tail = (float*)((u16*)d_ws + (size_t)4*CH*NELEM);
  float* p  = tail;          // NMAT (trace accumulators)
  float* f  = p + NMAT;      // CH   (frobenius accumulators)

  k_zero<<<2,256,0,stream>>>(p, NMAT + CH);
  for(int m0=0; m0<NMAT; m0+=CH){
    if(m0) k_zero<<<(CH+255)/256,256,0,stream>>>(f, CH);
    k_frob_part<<<dim3(CH,16),256,0,stream>>>(ir, vi, f, m0);
    k_init_t<<<dim3(6,6,CH),256,0,stream>>>(ir, vi, f, b[0], b[1], m0);

    int X=0, Y=1, f1=2, f2=3;
    dim3 gs(3*CH), gf(4*CH);
    // 5 quintic iterations: G=X^T X (via NT(Y,Y)); E=QB*G+QC*G^2; X'=QA*X+X*E; Y'=X'^T
    for(int q=0;q<5;q++){
      k_gemm<<<gs,256,0,stream>>>(b[Y],  b[Y],  b[f1], b[f1], nullptr, 1.f, 0.f, 1,
                                  nullptr, nullptr, nullptr, 0);
      k_gemm<<<gs,256,0,stream>>>(b[f1], b[f1], b[f2], b[f2], b[f1],   QC,  QB,  1,
                                  nullptr, nullptr, nullptr, 0);
      k_gemm<<<gf,256,0,stream>>>(b[X],  b[f2], b[f1], b[Y],  b[X],    1.f, QA,  0,
                                  nullptr, nullptr, nullptr, 0);
      int t=X; X=f1; f1=t;
    }
    // 3 cubic polish: X' = 1.5X - 0.5*X*G; final one fuses trace(X'.*(M+eps))
    for(int q=0;q<3;q++){
      k_gemm<<<gs,256,0,stream>>>(b[Y], b[Y],  b[f1], b[f1], nullptr, 1.f,   0.f, 1,
                                  nullptr, nullptr, nullptr, 0);
      if(q==2)
        k_gemm<<<gf,256,0,stream>>>(b[X], b[f1], b[f2], nullptr, b[X], -0.5f, 1.5f, 0,
                                    ir, vi, p, m0);
      else
        k_gemm<<<gf,256,0,stream>>>(b[X], b[f1], b[f2], b[Y], b[X], -0.5f, 1.5f, 0,
                                    nullptr, nullptr, nullptr, 0);
      int t=X; X=f2; f2=t;
    }
  }
  k_combine_w<<<(NCH*(NELEM/4))/256,256,0,stream>>>(ir, vi, p, out);
}